// Round 1
// baseline (664.494 us; speedup 1.0000x reference)
//
#include <hip/hip_runtime.h>
#include <hip/hip_bf16.h>
#include <stdint.h>

typedef __attribute__((ext_vector_type(8))) __bf16 bf16x8;
typedef __attribute__((ext_vector_type(4))) __bf16 bf16x4;
typedef __attribute__((ext_vector_type(4))) float f32x4;

typedef const __attribute__((address_space(1))) void* gas_ptr;
typedef __attribute__((address_space(3))) void* las_ptr;

static __device__ __forceinline__ void gload_lds16(const void* g, void* l) {
  __builtin_amdgcn_global_load_lds((gas_ptr)g, (las_ptr)l, 16, 0, 0);
}

// ---------------- generic transpose + fp32->bf16 ----------------
__global__ void transpose_cvt(const float* __restrict__ in, __bf16* __restrict__ out,
                              int R, int S) {
  __shared__ float t[32][33];
  int tx = threadIdx.x, ty = threadIdx.y;
  int r0 = blockIdx.y * 32, s0 = blockIdx.x * 32;
#pragma unroll
  for (int i = 0; i < 4; ++i) {
    int r = r0 + ty + i * 8;
    if (r < R && (s0 + tx) < S) t[ty + i * 8][tx] = in[(size_t)r * S + s0 + tx];
  }
  __syncthreads();
#pragma unroll
  for (int i = 0; i < 4; ++i) {
    int s = s0 + ty + i * 8;
    if (s < S && (r0 + tx) < R) out[(size_t)s * R + r0 + tx] = (__bf16)t[tx][ty + i * 8];
  }
}

// Wq/Wk/Wv [H=16][C=1024][HS=64] -> WqkvT bf16 [3*1024 rows][1024 cols]
// row n = sel*1024 + h*64 + d holds W_sel[h][:,d]
__global__ void qkv_repack(const float* __restrict__ Wq, const float* __restrict__ Wk,
                           const float* __restrict__ Wv, __bf16* __restrict__ outT) {
  __shared__ float t[32][33];
  int z = blockIdx.z, sel = z >> 4, h = z & 15;
  const float* in = (sel == 0 ? Wq : sel == 1 ? Wk : Wv) + (size_t)h * 1024 * 64;
  __bf16* out = outT + (size_t)(sel * 1024 + h * 64) * 1024;
  int tx = threadIdx.x, ty = threadIdx.y;
  int r0 = blockIdx.y * 32, s0 = blockIdx.x * 32;  // r over C, s over HS
#pragma unroll
  for (int i = 0; i < 4; ++i)
    t[ty + i * 8][tx] = in[(size_t)(r0 + ty + i * 8) * 64 + s0 + tx];
  __syncthreads();
#pragma unroll
  for (int i = 0; i < 4; ++i)
    out[(size_t)(s0 + ty + i * 8) * 1024 + r0 + tx] = (__bf16)t[tx][ty + i * 8];
}

// ---------------- LayerNorm (C=1024) -> bf16 ----------------
__global__ __launch_bounds__(256) void ln_kernel(const float* __restrict__ x,
                                                 const float* __restrict__ g,
                                                 const float* __restrict__ b,
                                                 __bf16* __restrict__ out) {
  __shared__ float red[8];
  int row = blockIdx.x, tid = threadIdx.x;
  float4 v = ((const float4*)(x + (size_t)row * 1024))[tid];
  float s = v.x + v.y + v.z + v.w;
  float s2 = v.x * v.x + v.y * v.y + v.z * v.z + v.w * v.w;
#pragma unroll
  for (int m = 1; m < 64; m <<= 1) { s += __shfl_xor(s, m); s2 += __shfl_xor(s2, m); }
  if ((tid & 63) == 0) { red[tid >> 6] = s; red[4 + (tid >> 6)] = s2; }
  __syncthreads();
  s = red[0] + red[1] + red[2] + red[3];
  s2 = red[4] + red[5] + red[6] + red[7];
  float mu = s * (1.0f / 1024.0f);
  float var = s2 * (1.0f / 1024.0f) - mu * mu;
  float rs = rsqrtf(var + 1e-5f);
  float4 gg = ((const float4*)g)[tid];
  float4 bb = ((const float4*)b)[tid];
  bf16x4 o4;
  o4[0] = (__bf16)((v.x - mu) * rs * gg.x + bb.x);
  o4[1] = (__bf16)((v.y - mu) * rs * gg.y + bb.y);
  o4[2] = (__bf16)((v.z - mu) * rs * gg.z + bb.z);
  o4[3] = (__bf16)((v.w - mu) * rs * gg.w + bb.w);
  *(bf16x4*)(out + (size_t)row * 1024 + tid * 4) = o4;
}

// ---------------- GEMM: C[M,N] = A[M,K] * Bt[N,K]^T, m97 structure ----------------
// EPI 0: bf16 out            (QKV)
// EPI 1: f32 out = resid + acc + bias   (proj: resid = x)
// EPI 2: bf16 out = relu(acc + bias)    (FF1)
// EPI 3: f32 out = resid + acc + bias   (FF2: resid = x2, in-place on d_out)
template <int EPI>
__global__ __launch_bounds__(256) void gemm_bt(const __bf16* __restrict__ A,
                                               const __bf16* __restrict__ Bt,
                                               void* __restrict__ Cout,
                                               const float* __restrict__ bias,
                                               const float* __restrict__ resid,
                                               int M, int N, int K) {
  __shared__ __align__(16) __bf16 Alds[128 * 32];
  __shared__ __align__(16) __bf16 Blds[128 * 32];
  int tid = threadIdx.x;
  int n0 = blockIdx.x * 128, m0 = blockIdx.y * 128;
  int lane = tid & 63, w = tid >> 6;
  int wr = (w >> 1) * 64, wc = (w & 1) * 64;
  int lr = lane & 15, lk = (lane >> 4) * 8;
  f32x4 acc[4][4];
#pragma unroll
  for (int mi = 0; mi < 4; ++mi)
#pragma unroll
    for (int ni = 0; ni < 4; ++ni)
#pragma unroll
      for (int e = 0; e < 4; ++e) acc[mi][ni][e] = 0.0f;

  int sr = tid >> 2, sc = (tid & 3) * 8;  // staging: row (0..63), col chunk
  const __bf16* ga = A + (size_t)(m0 + sr) * K + sc;
  const __bf16* gb = Bt + (size_t)(n0 + sr) * K + sc;
  __bf16* la = Alds + tid * 8;  // byte offset tid*16
  __bf16* lb = Blds + tid * 8;

  for (int k0 = 0; k0 < K; k0 += 32) {
    gload_lds16(ga + k0, la);
    gload_lds16(ga + (size_t)64 * K + k0, la + 64 * 32);
    gload_lds16(gb + k0, lb);
    gload_lds16(gb + (size_t)64 * K + k0, lb + 64 * 32);
    __syncthreads();
    bf16x8 af[4], bfr[4];
#pragma unroll
    for (int i = 0; i < 4; ++i) af[i] = *(const bf16x8*)&Alds[(wr + i * 16 + lr) * 32 + lk];
#pragma unroll
    for (int i = 0; i < 4; ++i) bfr[i] = *(const bf16x8*)&Blds[(wc + i * 16 + lr) * 32 + lk];
#pragma unroll
    for (int mi = 0; mi < 4; ++mi)
#pragma unroll
      for (int ni = 0; ni < 4; ++ni)
        acc[mi][ni] = __builtin_amdgcn_mfma_f32_16x16x32_bf16(af[mi], bfr[ni], acc[mi][ni], 0, 0, 0);
    __syncthreads();
  }

  int rb = m0 + wr + (lane >> 4) * 4;
  int cb = n0 + wc + lr;
#pragma unroll
  for (int mi = 0; mi < 4; ++mi) {
#pragma unroll
    for (int r = 0; r < 4; ++r) {
      int row = rb + mi * 16 + r;
#pragma unroll
      for (int ni = 0; ni < 4; ++ni) {
        int col = cb + ni * 16;
        float v = acc[mi][ni][r];
        size_t idx = (size_t)row * N + col;
        if (EPI == 0) {
          ((__bf16*)Cout)[idx] = (__bf16)v;
        } else if (EPI == 1) {
          ((float*)Cout)[idx] = resid[idx] + v + bias[col];
        } else if (EPI == 2) {
          v += bias[col];
          ((__bf16*)Cout)[idx] = (__bf16)fmaxf(v, 0.0f);
        } else {
          ((float*)Cout)[idx] = resid[idx] + v + bias[col];
        }
      }
    }
  }
}

// ---------------- causal flash attention ----------------
// qkv: bf16 [B][T][3*1024], row layout [q(1024) | k(1024) | v(1024)], head h at h*64
// o:   bf16 [B][T][1024]
__global__ __launch_bounds__(64) void attn_kernel(const __bf16* __restrict__ qkv,
                                                  __bf16* __restrict__ o) {
  __shared__ __align__(16) __bf16 P_lds[16 * 32];
  __shared__ __align__(16) __bf16 Vt_lds[64 * 32];
  int l = threadIdx.x;
  int qt0 = blockIdx.x * 16;
  int bh = blockIdx.y;
  int b = bh >> 4, h = bh & 15;
  const __bf16* base = qkv + (size_t)b * 2048 * 3072;
  int lr = l & 15, lk = (l >> 4) * 8;

  const __bf16* qrow = base + (size_t)(qt0 + lr) * 3072 + h * 64;
  bf16x8 qa0 = *(const bf16x8*)(qrow + lk);
  bf16x8 qa1 = *(const bf16x8*)(qrow + 32 + lk);

  f32x4 oacc[4];
  float m_acc[4], l_acc[4];
#pragma unroll
  for (int n = 0; n < 4; ++n)
#pragma unroll
    for (int e = 0; e < 4; ++e) oacc[n][e] = 0.0f;
#pragma unroll
  for (int r = 0; r < 4; ++r) { m_acc[r] = -__builtin_inff(); l_acc[r] = 0.0f; }

  int vkey = l & 31, vdb = (l >> 5) * 32;
  int nkb = (qt0 + 16 + 31) >> 5;
  for (int kb = 0; kb < nkb; ++kb) {
    int s0 = kb * 32;
    // QK^T: two 16-key halves, K-dim 64 (2 mfma each)
    f32x4 sv[2];
#pragma unroll
    for (int hh = 0; hh < 2; ++hh) {
      const __bf16* krow = base + (size_t)(s0 + hh * 16 + lr) * 3072 + 1024 + h * 64;
      bf16x8 k0 = *(const bf16x8*)(krow + lk);
      bf16x8 k1 = *(const bf16x8*)(krow + 32 + lk);
      f32x4 z;
#pragma unroll
      for (int e = 0; e < 4; ++e) z[e] = 0.0f;
      z = __builtin_amdgcn_mfma_f32_16x16x32_bf16(qa0, k0, z, 0, 0, 0);
      z = __builtin_amdgcn_mfma_f32_16x16x32_bf16(qa1, k1, z, 0, 0, 0);
      sv[hh] = z;
    }
    // scale + causal mask (scale = C^-0.5 = 1/32)
#pragma unroll
    for (int hh = 0; hh < 2; ++hh)
#pragma unroll
      for (int r = 0; r < 4; ++r) {
        int row = qt0 + (l >> 4) * 4 + r;
        int col = s0 + hh * 16 + lr;
        float sval = sv[hh][r] * 0.03125f;
        sv[hh][r] = (col <= row) ? sval : -__builtin_inff();
      }
    // V tile load to regs (transposed into LDS later)
    const __bf16* vrow = base + (size_t)(s0 + vkey) * 3072 + 2048 + h * 64 + vdb;
    bf16x8 vv[4];
#pragma unroll
    for (int j = 0; j < 4; ++j) vv[j] = *(const bf16x8*)(vrow + j * 8);
    // online softmax: row max over the 16 cols in each half and the 16 lanes
    float mb[4];
#pragma unroll
    for (int r = 0; r < 4; ++r) mb[r] = fmaxf(sv[0][r], sv[1][r]);
#pragma unroll
    for (int mm = 1; mm < 16; mm <<= 1)
#pragma unroll
      for (int r = 0; r < 4; ++r) mb[r] = fmaxf(mb[r], __shfl_xor(mb[r], mm));
    float sc[4];
#pragma unroll
    for (int r = 0; r < 4; ++r) {
      float mnew = fmaxf(m_acc[r], mb[r]);
      sc[r] = __expf(m_acc[r] - mnew);
      m_acc[r] = mnew;
    }
    float p0[4], p1[4], ps[4];
#pragma unroll
    for (int r = 0; r < 4; ++r) {
      p0[r] = __expf(sv[0][r] - m_acc[r]);
      p1[r] = __expf(sv[1][r] - m_acc[r]);
      ps[r] = p0[r] + p1[r];
    }
#pragma unroll
    for (int mm = 1; mm < 16; mm <<= 1)
#pragma unroll
      for (int r = 0; r < 4; ++r) ps[r] += __shfl_xor(ps[r], mm);
#pragma unroll
    for (int r = 0; r < 4; ++r) l_acc[r] = l_acc[r] * sc[r] + ps[r];
#pragma unroll
    for (int n = 0; n < 4; ++n)
#pragma unroll
      for (int r = 0; r < 4; ++r) oacc[n][r] *= sc[r];
    // stage P (bf16) and V^T into LDS
    __syncthreads();
#pragma unroll
    for (int r = 0; r < 4; ++r) {
      int prow = (l >> 4) * 4 + r;
      P_lds[prow * 32 + lr] = (__bf16)p0[r];
      P_lds[prow * 32 + 16 + lr] = (__bf16)p1[r];
    }
#pragma unroll
    for (int j = 0; j < 4; ++j)
#pragma unroll
      for (int e = 0; e < 8; ++e)
        Vt_lds[(vdb + j * 8 + e) * 32 + vkey] = vv[j][e];
    __syncthreads();
    // PV: K-dim = 32 keys, 4 dim-fragments
    bf16x8 pf = *(const bf16x8*)&P_lds[lr * 32 + lk];
#pragma unroll
    for (int n = 0; n < 4; ++n) {
      bf16x8 vf = *(const bf16x8*)&Vt_lds[(n * 16 + lr) * 32 + lk];
      oacc[n] = __builtin_amdgcn_mfma_f32_16x16x32_bf16(pf, vf, oacc[n], 0, 0, 0);
    }
  }
  // write O
  __bf16* obase = o + (size_t)b * 2048 * 1024 + h * 64;
#pragma unroll
  for (int r = 0; r < 4; ++r) {
    int row = qt0 + (l >> 4) * 4 + r;
    float inv = 1.0f / l_acc[r];
#pragma unroll
    for (int n = 0; n < 4; ++n)
      obase[(size_t)row * 1024 + n * 16 + lr] = (__bf16)(oacc[n][r] * inv);
  }
}

// ---------------- launcher ----------------
extern "C" void kernel_launch(void* const* d_in, const int* in_sizes, int n_in,
                              void* d_out, int out_size, void* d_ws, size_t ws_size,
                              hipStream_t stream) {
  const float* x     = (const float*)d_in[0];
  const float* Wq    = (const float*)d_in[1];
  const float* Wk    = (const float*)d_in[2];
  const float* Wv    = (const float*)d_in[3];
  const float* Wproj = (const float*)d_in[4];
  const float* bproj = (const float*)d_in[5];
  const float* ln1_g = (const float*)d_in[6];
  const float* ln1_b = (const float*)d_in[7];
  const float* ln2_g = (const float*)d_in[8];
  const float* ln2_b = (const float*)d_in[9];
  const float* W1    = (const float*)d_in[10];
  const float* b1    = (const float*)d_in[11];
  const float* W2    = (const float*)d_in[12];
  const float* b2    = (const float*)d_in[13];
  float* out = (float*)d_out;

  char* ws = (char*)d_ws;
  __bf16* actA   = (__bf16*)(ws + 0);          // 16 MB: h (ln1) then h2 (ln2)
  __bf16* WqkvT  = (__bf16*)(ws + 16777216);   // 6 MB
  __bf16* WprojT = (__bf16*)(ws + 23068672);   // 2 MB
  __bf16* W1T    = (__bf16*)(ws + 25165824);   // 8 MB
  __bf16* W2T    = (__bf16*)(ws + 33554432);   // 8 MB
  __bf16* qkvbuf = (__bf16*)(ws + 41943040);   // 64 MB: qkv, later ff1
  __bf16* obuf   = (__bf16*)(ws + 109051904);  // 16 MB
  __bf16* ff1    = qkvbuf;

  dim3 t32x8(32, 8);
  qkv_repack<<<dim3(2, 32, 48), t32x8, 0, stream>>>(Wq, Wk, Wv, WqkvT);
  transpose_cvt<<<dim3(32, 32), t32x8, 0, stream>>>(Wproj, WprojT, 1024, 1024);
  transpose_cvt<<<dim3(128, 32), t32x8, 0, stream>>>(W1, W1T, 1024, 4096);
  transpose_cvt<<<dim3(32, 128), t32x8, 0, stream>>>(W2, W2T, 4096, 1024);

  ln_kernel<<<8192, 256, 0, stream>>>(x, ln1_g, ln1_b, actA);
  gemm_bt<0><<<dim3(24, 64), 256, 0, stream>>>(actA, WqkvT, qkvbuf, nullptr, nullptr,
                                               8192, 3072, 1024);
  attn_kernel<<<dim3(128, 64), 64, 0, stream>>>(qkvbuf, obuf);
  gemm_bt<1><<<dim3(8, 64), 256, 0, stream>>>(obuf, WprojT, out, bproj, x,
                                              8192, 1024, 1024);
  ln_kernel<<<8192, 256, 0, stream>>>(out, ln2_g, ln2_b, actA);
  gemm_bt<2><<<dim3(32, 64), 256, 0, stream>>>(actA, W1T, ff1, b1, nullptr,
                                               8192, 4096, 1024);
  gemm_bt<3><<<dim3(8, 64), 256, 0, stream>>>(ff1, W2T, out, b2, out,
                                              8192, 1024, 4096);
}

// Round 2
// 611.880 us; speedup vs baseline: 1.0860x; 1.0860x over previous
//
#include <hip/hip_runtime.h>
#include <hip/hip_bf16.h>
#include <stdint.h>

typedef __attribute__((ext_vector_type(8))) __bf16 bf16x8;
typedef __attribute__((ext_vector_type(4))) __bf16 bf16x4;
typedef __attribute__((ext_vector_type(4))) float f32x4;

typedef const __attribute__((address_space(1))) void* gas_ptr;
typedef __attribute__((address_space(3))) void* las_ptr;

static __device__ __forceinline__ void gload_lds16(const void* g, void* l) {
  __builtin_amdgcn_global_load_lds((gas_ptr)g, (las_ptr)l, 16, 0, 0);
}

// ---------------- generic transpose + fp32->bf16 ----------------
__global__ void transpose_cvt(const float* __restrict__ in, __bf16* __restrict__ out,
                              int R, int S) {
  __shared__ float t[32][33];
  int tx = threadIdx.x, ty = threadIdx.y;
  int r0 = blockIdx.y * 32, s0 = blockIdx.x * 32;
#pragma unroll
  for (int i = 0; i < 4; ++i) {
    int r = r0 + ty + i * 8;
    if (r < R && (s0 + tx) < S) t[ty + i * 8][tx] = in[(size_t)r * S + s0 + tx];
  }
  __syncthreads();
#pragma unroll
  for (int i = 0; i < 4; ++i) {
    int s = s0 + ty + i * 8;
    if (s < S && (r0 + tx) < R) out[(size_t)s * R + r0 + tx] = (__bf16)t[tx][ty + i * 8];
  }
}

// Wq/Wk/Wv [H=16][C=1024][HS=64] -> WqkvT bf16 [3*1024 rows][1024 cols]
// row n = sel*1024 + h*64 + d holds W_sel[h][:,d]
__global__ void qkv_repack(const float* __restrict__ Wq, const float* __restrict__ Wk,
                           const float* __restrict__ Wv, __bf16* __restrict__ outT) {
  __shared__ float t[32][33];
  int z = blockIdx.z, sel = z >> 4, h = z & 15;
  const float* in = (sel == 0 ? Wq : sel == 1 ? Wk : Wv) + (size_t)h * 1024 * 64;
  __bf16* out = outT + (size_t)(sel * 1024 + h * 64) * 1024;
  int tx = threadIdx.x, ty = threadIdx.y;
  int r0 = blockIdx.y * 32, s0 = blockIdx.x * 32;  // r over C, s over HS
#pragma unroll
  for (int i = 0; i < 4; ++i)
    t[ty + i * 8][tx] = in[(size_t)(r0 + ty + i * 8) * 64 + s0 + tx];
  __syncthreads();
#pragma unroll
  for (int i = 0; i < 4; ++i)
    out[(size_t)(s0 + ty + i * 8) * 1024 + r0 + tx] = (__bf16)t[tx][ty + i * 8];
}

// ---------------- LayerNorm (C=1024) -> bf16 ----------------
__global__ __launch_bounds__(256) void ln_kernel(const float* __restrict__ x,
                                                 const float* __restrict__ g,
                                                 const float* __restrict__ b,
                                                 __bf16* __restrict__ out) {
  __shared__ float red[8];
  int row = blockIdx.x, tid = threadIdx.x;
  float4 v = ((const float4*)(x + (size_t)row * 1024))[tid];
  float s = v.x + v.y + v.z + v.w;
  float s2 = v.x * v.x + v.y * v.y + v.z * v.z + v.w * v.w;
#pragma unroll
  for (int m = 1; m < 64; m <<= 1) { s += __shfl_xor(s, m); s2 += __shfl_xor(s2, m); }
  if ((tid & 63) == 0) { red[tid >> 6] = s; red[4 + (tid >> 6)] = s2; }
  __syncthreads();
  s = red[0] + red[1] + red[2] + red[3];
  s2 = red[4] + red[5] + red[6] + red[7];
  float mu = s * (1.0f / 1024.0f);
  float var = s2 * (1.0f / 1024.0f) - mu * mu;
  float rs = rsqrtf(var + 1e-5f);
  float4 gg = ((const float4*)g)[tid];
  float4 bb = ((const float4*)b)[tid];
  bf16x4 o4;
  o4[0] = (__bf16)((v.x - mu) * rs * gg.x + bb.x);
  o4[1] = (__bf16)((v.y - mu) * rs * gg.y + bb.y);
  o4[2] = (__bf16)((v.z - mu) * rs * gg.z + bb.z);
  o4[3] = (__bf16)((v.w - mu) * rs * gg.w + bb.w);
  *(bf16x4*)(out + (size_t)row * 1024 + tid * 4) = o4;
}

// ---------------- GEMM: C[M,N] = A[M,K] * Bt[N,K]^T, m97 structure ----------------
// EPI 0: bf16 out
// EPI 1: f32 out = resid + acc + bias   (proj: resid = x)
// EPI 2: bf16 out = relu(acc + bias)    (FF1)
// EPI 3: f32 out = resid + acc + bias   (FF2)
// EPI 4: QKV split-scatter into Qh [BH][T][64], Kh [BH][T][64], Vt [BH][64][T]
template <int EPI>
__global__ __launch_bounds__(256) void gemm_bt(const __bf16* __restrict__ A,
                                               const __bf16* __restrict__ Bt,
                                               void* __restrict__ Cout,
                                               const float* __restrict__ bias,
                                               const float* __restrict__ resid,
                                               __bf16* __restrict__ q_out,
                                               __bf16* __restrict__ k_out,
                                               __bf16* __restrict__ vt_out,
                                               int M, int N, int K) {
  __shared__ __align__(16) __bf16 Alds[128 * 32];
  __shared__ __align__(16) __bf16 Blds[128 * 32];
  int tid = threadIdx.x;
  int n0 = blockIdx.x * 128, m0 = blockIdx.y * 128;
  int lane = tid & 63, w = tid >> 6;
  int wr = (w >> 1) * 64, wc = (w & 1) * 64;
  int lr = lane & 15, lk = (lane >> 4) * 8;
  f32x4 acc[4][4];
#pragma unroll
  for (int mi = 0; mi < 4; ++mi)
#pragma unroll
    for (int ni = 0; ni < 4; ++ni)
#pragma unroll
      for (int e = 0; e < 4; ++e) acc[mi][ni][e] = 0.0f;

  int sr = tid >> 2, sc = (tid & 3) * 8;
  const __bf16* ga = A + (size_t)(m0 + sr) * K + sc;
  const __bf16* gb = Bt + (size_t)(n0 + sr) * K + sc;
  __bf16* la = Alds + tid * 8;
  __bf16* lb = Blds + tid * 8;

  for (int k0 = 0; k0 < K; k0 += 32) {
    gload_lds16(ga + k0, la);
    gload_lds16(ga + (size_t)64 * K + k0, la + 64 * 32);
    gload_lds16(gb + k0, lb);
    gload_lds16(gb + (size_t)64 * K + k0, lb + 64 * 32);
    __syncthreads();
    bf16x8 af[4], bfr[4];
#pragma unroll
    for (int i = 0; i < 4; ++i) af[i] = *(const bf16x8*)&Alds[(wr + i * 16 + lr) * 32 + lk];
#pragma unroll
    for (int i = 0; i < 4; ++i) bfr[i] = *(const bf16x8*)&Blds[(wc + i * 16 + lr) * 32 + lk];
#pragma unroll
    for (int mi = 0; mi < 4; ++mi)
#pragma unroll
      for (int ni = 0; ni < 4; ++ni)
        acc[mi][ni] = __builtin_amdgcn_mfma_f32_16x16x32_bf16(af[mi], bfr[ni], acc[mi][ni], 0, 0, 0);
    __syncthreads();
  }

  int rb = m0 + wr + (lane >> 4) * 4;
  int cb = n0 + wc + lr;
#pragma unroll
  for (int mi = 0; mi < 4; ++mi) {
#pragma unroll
    for (int r = 0; r < 4; ++r) {
      int row = rb + mi * 16 + r;
#pragma unroll
      for (int ni = 0; ni < 4; ++ni) {
        int col = cb + ni * 16;
        float v = acc[mi][ni][r];
        size_t idx = (size_t)row * N + col;
        if (EPI == 0) {
          ((__bf16*)Cout)[idx] = (__bf16)v;
        } else if (EPI == 1) {
          ((float*)Cout)[idx] = resid[idx] + v + bias[col];
        } else if (EPI == 2) {
          v += bias[col];
          ((__bf16*)Cout)[idx] = (__bf16)fmaxf(v, 0.0f);
        } else if (EPI == 3) {
          ((float*)Cout)[idx] = resid[idx] + v + bias[col];
        } else {
          int b = row >> 11, t = row & 2047;
          int sel = col >> 10, cc = col & 1023, h = cc >> 6, d = cc & 63;
          int bh = b * 16 + h;
          __bf16 val = (__bf16)v;
          if (sel == 0)
            q_out[((size_t)bh * 2048 + t) * 64 + d] = val;
          else if (sel == 1)
            k_out[((size_t)bh * 2048 + t) * 64 + d] = val;
          else
            vt_out[((size_t)bh * 64 + d) * 2048 + t] = val;
        }
      }
    }
  }
}

// ---------------- causal flash attention v2 ----------------
// 4 waves/block, QBLK=64 (16 q/wave), KVBLK=64.
// Qh/Kh: bf16 [BH][T][64]; Vt: bf16 [BH][64][T]; o: bf16 [B][T][1024]
__global__ __launch_bounds__(256) void attn_kernel2(const __bf16* __restrict__ Qh,
                                                    const __bf16* __restrict__ Kh,
                                                    const __bf16* __restrict__ Vt,
                                                    __bf16* __restrict__ o) {
  __shared__ __align__(16) char Klds[8192];   // 64 keys x 128B, XOR-swizzled
  __shared__ __align__(16) char Vlds[8192];   // 64 dims x 128B (keys), XOR-swizzled
  __shared__ __align__(16) char Plds[8192];   // per-wave 16 q x 128B, XOR-swizzled
  int tid = threadIdx.x;
  int l = tid & 63, w = tid >> 6;
  int lr = l & 15, lg = l >> 4;
  int qt0 = blockIdx.x * 64;
  int bh = blockIdx.y;
  int qw0 = qt0 + w * 16;

  const char* Kbase = (const char*)(Kh + (size_t)bh * 2048 * 64);
  const char* Vbase = (const char*)(Vt + (size_t)bh * 64 * 2048);
  const __bf16* qrow = Qh + ((size_t)bh * 2048 + qw0 + lr) * 64 + lg * 8;
  bf16x8 qa0 = *(const bf16x8*)qrow;
  bf16x8 qa1 = *(const bf16x8*)(qrow + 32);

  // staging: thread stages 16B; rows srow and srow+32; source pre-swizzled (m173)
  int srow = tid >> 3;
  int schunk = (tid & 7) * 16;
  int sw0 = (srow & 7) << 4;  // rows srow and srow+32 share (row&7)
  char* kd0 = Klds + tid * 16;
  char* kd1 = Klds + 4096 + tid * 16;
  char* vd0 = Vlds + tid * 16;
  char* vd1 = Vlds + 4096 + tid * 16;
  char* Pw = Plds + w * 2048;

  f32x4 oacc[4];
  float m_acc[4], l_acc[4];
#pragma unroll
  for (int n = 0; n < 4; ++n)
#pragma unroll
    for (int e = 0; e < 4; ++e) oacc[n][e] = 0.0f;
#pragma unroll
  for (int r = 0; r < 4; ++r) { m_acc[r] = -3.0e38f; l_acc[r] = 0.0f; }

  int c0 = lg * 16, c1 = 64 + lg * 16;  // k-chunk byte offsets within a 128B row
  int qrb = qw0 + lg * 4;
  int nkb = blockIdx.x + 1;

  for (int kb = 0; kb < nkb; ++kb) {
    int s0 = kb * 64;
    __syncthreads();  // previous iteration's LDS reads complete
    gload_lds16(Kbase + (size_t)(s0 + srow) * 128 + (schunk ^ sw0), kd0);
    gload_lds16(Kbase + (size_t)(s0 + srow + 32) * 128 + (schunk ^ sw0), kd1);
    gload_lds16(Vbase + (size_t)srow * 4096 + s0 * 2 + (schunk ^ sw0), vd0);
    gload_lds16(Vbase + (size_t)(srow + 32) * 4096 + s0 * 2 + (schunk ^ sw0), vd1);
    __syncthreads();  // staging complete (vmcnt drained by barrier)

    // QK^T: 64 keys in 4 groups, K-dim 64 (2 mfma per group)
    f32x4 sv[4];
#pragma unroll
    for (int kg = 0; kg < 4; ++kg) {
      int key = kg * 16 + lr, sw = (key & 7) << 4;
      bf16x8 k0 = *(const bf16x8*)(Klds + key * 128 + (c0 ^ sw));
      bf16x8 k1 = *(const bf16x8*)(Klds + key * 128 + (c1 ^ sw));
      f32x4 z = {0.f, 0.f, 0.f, 0.f};
      z = __builtin_amdgcn_mfma_f32_16x16x32_bf16(qa0, k0, z, 0, 0, 0);
      z = __builtin_amdgcn_mfma_f32_16x16x32_bf16(qa1, k1, z, 0, 0, 0);
      sv[kg] = z;
    }
    // scale (C^-0.5 = 1/32) + causal mask
#pragma unroll
    for (int kg = 0; kg < 4; ++kg) {
      int col = s0 + kg * 16 + lr;
#pragma unroll
      for (int r = 0; r < 4; ++r) {
        float xv = sv[kg][r] * 0.03125f;
        sv[kg][r] = (col <= qrb + r) ? xv : -3.0e38f;
      }
    }
    // online softmax (16-lane groups)
    float mb[4];
#pragma unroll
    for (int r = 0; r < 4; ++r)
      mb[r] = fmaxf(fmaxf(sv[0][r], sv[1][r]), fmaxf(sv[2][r], sv[3][r]));
#pragma unroll
    for (int mm = 1; mm < 16; mm <<= 1)
#pragma unroll
      for (int r = 0; r < 4; ++r) mb[r] = fmaxf(mb[r], __shfl_xor(mb[r], mm));
    float sc[4], ps[4];
#pragma unroll
    for (int r = 0; r < 4; ++r) {
      float mnew = fmaxf(m_acc[r], mb[r]);
      sc[r] = __expf(m_acc[r] - mnew);
      m_acc[r] = mnew;
    }
#pragma unroll
    for (int kg = 0; kg < 4; ++kg)
#pragma unroll
      for (int r = 0; r < 4; ++r) sv[kg][r] = __expf(sv[kg][r] - m_acc[r]);
#pragma unroll
    for (int r = 0; r < 4; ++r)
      ps[r] = (sv[0][r] + sv[1][r]) + (sv[2][r] + sv[3][r]);
#pragma unroll
    for (int mm = 1; mm < 16; mm <<= 1)
#pragma unroll
      for (int r = 0; r < 4; ++r) ps[r] += __shfl_xor(ps[r], mm);
#pragma unroll
    for (int r = 0; r < 4; ++r) l_acc[r] = l_acc[r] * sc[r] + ps[r];
#pragma unroll
    for (int n = 0; n < 4; ++n)
#pragma unroll
      for (int r = 0; r < 4; ++r) oacc[n][r] *= sc[r];

    // P -> per-wave LDS (bf16, swizzled); read back as A-fragments (same wave,
    // lgkmcnt-ordered by compiler; no barrier needed)
#pragma unroll
    for (int kg = 0; kg < 4; ++kg)
#pragma unroll
      for (int r = 0; r < 4; ++r) {
        int qr = lg * 4 + r;
        *(__bf16*)(Pw + qr * 128 + (((kg * 16 + lr) * 2) ^ ((qr & 7) << 4))) =
            (__bf16)sv[kg][r];
      }
    int swp = (lr & 7) << 4;
    bf16x8 pf0 = *(const bf16x8*)(Pw + lr * 128 + (c0 ^ swp));
    bf16x8 pf1 = *(const bf16x8*)(Pw + lr * 128 + (c1 ^ swp));
#pragma unroll
    for (int n = 0; n < 4; ++n) {
      int row = n * 16 + lr, sw = (row & 7) << 4;
      bf16x8 v0 = *(const bf16x8*)(Vlds + row * 128 + (c0 ^ sw));
      bf16x8 v1 = *(const bf16x8*)(Vlds + row * 128 + (c1 ^ sw));
      oacc[n] = __builtin_amdgcn_mfma_f32_16x16x32_bf16(pf0, v0, oacc[n], 0, 0, 0);
      oacc[n] = __builtin_amdgcn_mfma_f32_16x16x32_bf16(pf1, v1, oacc[n], 0, 0, 0);
    }
  }

  __bf16* obase = o + ((size_t)(bh >> 4) * 2048 + qw0) * 1024 + (bh & 15) * 64;
#pragma unroll
  for (int r = 0; r < 4; ++r) {
    float inv = 1.0f / l_acc[r];
#pragma unroll
    for (int n = 0; n < 4; ++n)
      obase[(size_t)(lg * 4 + r) * 1024 + n * 16 + lr] = (__bf16)(oacc[n][r] * inv);
  }
}

// ---------------- launcher ----------------
extern "C" void kernel_launch(void* const* d_in, const int* in_sizes, int n_in,
                              void* d_out, int out_size, void* d_ws, size_t ws_size,
                              hipStream_t stream) {
  const float* x     = (const float*)d_in[0];
  const float* Wq    = (const float*)d_in[1];
  const float* Wk    = (const float*)d_in[2];
  const float* Wv    = (const float*)d_in[3];
  const float* Wproj = (const float*)d_in[4];
  const float* bproj = (const float*)d_in[5];
  const float* ln1_g = (const float*)d_in[6];
  const float* ln1_b = (const float*)d_in[7];
  const float* ln2_g = (const float*)d_in[8];
  const float* ln2_b = (const float*)d_in[9];
  const float* W1    = (const float*)d_in[10];
  const float* b1    = (const float*)d_in[11];
  const float* W2    = (const float*)d_in[12];
  const float* b2    = (const float*)d_in[13];
  float* out = (float*)d_out;

  char* ws = (char*)d_ws;
  __bf16* actA   = (__bf16*)(ws + 0);          // 16 MB
  __bf16* WqkvT  = (__bf16*)(ws + 16777216);   // 6 MB
  __bf16* WprojT = (__bf16*)(ws + 23068672);   // 2 MB
  __bf16* W1T    = (__bf16*)(ws + 25165824);   // 8 MB
  __bf16* W2T    = (__bf16*)(ws + 33554432);   // 8 MB
  __bf16* Qh     = (__bf16*)(ws + 41943040);   // 16 MB
  __bf16* Kh     = (__bf16*)(ws + 58720256);   // 16 MB
  __bf16* Vt     = (__bf16*)(ws + 75497472);   // 16 MB
  __bf16* obuf   = (__bf16*)(ws + 92274688);   // 16 MB
  __bf16* ff1    = Qh;                         // 64 MB, reuses Qh..obuf (dead by then)

  dim3 t32x8(32, 8);
  qkv_repack<<<dim3(2, 32, 48), t32x8, 0, stream>>>(Wq, Wk, Wv, WqkvT);
  transpose_cvt<<<dim3(32, 32), t32x8, 0, stream>>>(Wproj, WprojT, 1024, 1024);
  transpose_cvt<<<dim3(128, 32), t32x8, 0, stream>>>(W1, W1T, 1024, 4096);
  transpose_cvt<<<dim3(32, 128), t32x8, 0, stream>>>(W2, W2T, 4096, 1024);

  ln_kernel<<<8192, 256, 0, stream>>>(x, ln1_g, ln1_b, actA);
  gemm_bt<4><<<dim3(24, 64), 256, 0, stream>>>(actA, WqkvT, nullptr, nullptr, nullptr,
                                               Qh, Kh, Vt, 8192, 3072, 1024);
  attn_kernel2<<<dim3(32, 64), 256, 0, stream>>>(Qh, Kh, Vt, obuf);
  gemm_bt<1><<<dim3(8, 64), 256, 0, stream>>>(obuf, WprojT, out, bproj, x,
                                              nullptr, nullptr, nullptr, 8192, 1024, 1024);
  ln_kernel<<<8192, 256, 0, stream>>>(out, ln2_g, ln2_b, actA);
  gemm_bt<2><<<dim3(32, 64), 256, 0, stream>>>(actA, W1T, ff1, b1, nullptr,
                                               nullptr, nullptr, nullptr, 8192, 4096, 1024);
  gemm_bt<3><<<dim3(8, 64), 256, 0, stream>>>(ff1, W2T, out, b2, out,
                                              nullptr, nullptr, nullptr, 8192, 1024, 4096);
}

// Round 3
// 464.056 us; speedup vs baseline: 1.4319x; 1.3185x over previous
//
#include <hip/hip_runtime.h>
#include <hip/hip_bf16.h>
#include <stdint.h>

typedef __attribute__((ext_vector_type(8))) __bf16 bf16x8;
typedef __attribute__((ext_vector_type(4))) __bf16 bf16x4;
typedef __attribute__((ext_vector_type(4))) float f32x4;
typedef __attribute__((ext_vector_type(16))) float f32x16;
typedef __attribute__((ext_vector_type(4))) unsigned int u32x4;

typedef const __attribute__((address_space(1))) void* gas_ptr;
typedef __attribute__((address_space(3))) void* las_ptr;

static __device__ __forceinline__ void gload_lds16(const void* g, void* l) {
  __builtin_amdgcn_global_load_lds((gas_ptr)g, (las_ptr)l, 16, 0, 0);
}

static __device__ __forceinline__ unsigned int cvt_pk(float lo, float hi) {
  unsigned int r;
  asm("v_cvt_pk_bf16_f32 %0, %1, %2" : "=v"(r) : "v"(lo), "v"(hi));
  return r;
}

static __device__ __forceinline__ bf16x8 pack_frag(unsigned int a, unsigned int b,
                                                   unsigned int c, unsigned int d) {
  u32x4 t = {a, b, c, d};
  return __builtin_bit_cast(bf16x8, t);
}

// ---------------- generic transpose + fp32->bf16 ----------------
__global__ void transpose_cvt(const float* __restrict__ in, __bf16* __restrict__ out,
                              int R, int S) {
  __shared__ float t[32][33];
  int tx = threadIdx.x, ty = threadIdx.y;
  int r0 = blockIdx.y * 32, s0 = blockIdx.x * 32;
#pragma unroll
  for (int i = 0; i < 4; ++i) {
    int r = r0 + ty + i * 8;
    if (r < R && (s0 + tx) < S) t[ty + i * 8][tx] = in[(size_t)r * S + s0 + tx];
  }
  __syncthreads();
#pragma unroll
  for (int i = 0; i < 4; ++i) {
    int s = s0 + ty + i * 8;
    if (s < S && (r0 + tx) < R) out[(size_t)s * R + r0 + tx] = (__bf16)t[tx][ty + i * 8];
  }
}

// Wq/Wk/Wv [H=16][C=1024][HS=64] -> WqkvT bf16 [3*1024 rows][1024 cols]
__global__ void qkv_repack(const float* __restrict__ Wq, const float* __restrict__ Wk,
                           const float* __restrict__ Wv, __bf16* __restrict__ outT) {
  __shared__ float t[32][33];
  int z = blockIdx.z, sel = z >> 4, h = z & 15;
  const float* in = (sel == 0 ? Wq : sel == 1 ? Wk : Wv) + (size_t)h * 1024 * 64;
  __bf16* out = outT + (size_t)(sel * 1024 + h * 64) * 1024;
  int tx = threadIdx.x, ty = threadIdx.y;
  int r0 = blockIdx.y * 32, s0 = blockIdx.x * 32;
#pragma unroll
  for (int i = 0; i < 4; ++i)
    t[ty + i * 8][tx] = in[(size_t)(r0 + ty + i * 8) * 64 + s0 + tx];
  __syncthreads();
#pragma unroll
  for (int i = 0; i < 4; ++i)
    out[(size_t)(s0 + ty + i * 8) * 1024 + r0 + tx] = (__bf16)t[tx][ty + i * 8];
}

// ---------------- LayerNorm (C=1024) -> bf16 ----------------
__global__ __launch_bounds__(256) void ln_kernel(const float* __restrict__ x,
                                                 const float* __restrict__ g,
                                                 const float* __restrict__ b,
                                                 __bf16* __restrict__ out) {
  __shared__ float red[8];
  int row = blockIdx.x, tid = threadIdx.x;
  float4 v = ((const float4*)(x + (size_t)row * 1024))[tid];
  float s = v.x + v.y + v.z + v.w;
  float s2 = v.x * v.x + v.y * v.y + v.z * v.z + v.w * v.w;
#pragma unroll
  for (int m = 1; m < 64; m <<= 1) { s += __shfl_xor(s, m); s2 += __shfl_xor(s2, m); }
  if ((tid & 63) == 0) { red[tid >> 6] = s; red[4 + (tid >> 6)] = s2; }
  __syncthreads();
  s = red[0] + red[1] + red[2] + red[3];
  s2 = red[4] + red[5] + red[6] + red[7];
  float mu = s * (1.0f / 1024.0f);
  float var = s2 * (1.0f / 1024.0f) - mu * mu;
  float rs = rsqrtf(var + 1e-5f);
  float4 gg = ((const float4*)g)[tid];
  float4 bb = ((const float4*)b)[tid];
  bf16x4 o4;
  o4[0] = (__bf16)((v.x - mu) * rs * gg.x + bb.x);
  o4[1] = (__bf16)((v.y - mu) * rs * gg.y + bb.y);
  o4[2] = (__bf16)((v.z - mu) * rs * gg.z + bb.z);
  o4[3] = (__bf16)((v.w - mu) * rs * gg.w + bb.w);
  *(bf16x4*)(out + (size_t)row * 1024 + tid * 4) = o4;
}

// ---------------- GEMM: C[M,N] = A[M,K] * Bt[N,K]^T ----------------
// EPI 0: bf16 out
// EPI 1: f32 out = resid + acc + bias
// EPI 2: bf16 out = relu(acc + bias)
// EPI 3: f32 out = resid + acc + bias
// EPI 4: QKV split-scatter: Qt [BH][64][T], Kh [BH][T][64], Vt [BH][64][T]
template <int EPI>
__global__ __launch_bounds__(256) void gemm_bt(const __bf16* __restrict__ A,
                                               const __bf16* __restrict__ Bt,
                                               void* __restrict__ Cout,
                                               const float* __restrict__ bias,
                                               const float* __restrict__ resid,
                                               __bf16* __restrict__ q_out,
                                               __bf16* __restrict__ k_out,
                                               __bf16* __restrict__ vt_out,
                                               int M, int N, int K) {
  __shared__ __align__(16) __bf16 Alds[128 * 32];
  __shared__ __align__(16) __bf16 Blds[128 * 32];
  int tid = threadIdx.x;
  int n0 = blockIdx.x * 128, m0 = blockIdx.y * 128;
  int lane = tid & 63, w = tid >> 6;
  int wr = (w >> 1) * 64, wc = (w & 1) * 64;
  int lr = lane & 15, lk = (lane >> 4) * 8;
  f32x4 acc[4][4];
#pragma unroll
  for (int mi = 0; mi < 4; ++mi)
#pragma unroll
    for (int ni = 0; ni < 4; ++ni)
#pragma unroll
      for (int e = 0; e < 4; ++e) acc[mi][ni][e] = 0.0f;

  int sr = tid >> 2, sc = (tid & 3) * 8;
  const __bf16* ga = A + (size_t)(m0 + sr) * K + sc;
  const __bf16* gb = Bt + (size_t)(n0 + sr) * K + sc;
  __bf16* la = Alds + tid * 8;
  __bf16* lb = Blds + tid * 8;

  for (int k0 = 0; k0 < K; k0 += 32) {
    gload_lds16(ga + k0, la);
    gload_lds16(ga + (size_t)64 * K + k0, la + 64 * 32);
    gload_lds16(gb + k0, lb);
    gload_lds16(gb + (size_t)64 * K + k0, lb + 64 * 32);
    __syncthreads();
    bf16x8 af[4], bfr[4];
#pragma unroll
    for (int i = 0; i < 4; ++i) af[i] = *(const bf16x8*)&Alds[(wr + i * 16 + lr) * 32 + lk];
#pragma unroll
    for (int i = 0; i < 4; ++i) bfr[i] = *(const bf16x8*)&Blds[(wc + i * 16 + lr) * 32 + lk];
#pragma unroll
    for (int mi = 0; mi < 4; ++mi)
#pragma unroll
      for (int ni = 0; ni < 4; ++ni)
        acc[mi][ni] = __builtin_amdgcn_mfma_f32_16x16x32_bf16(af[mi], bfr[ni], acc[mi][ni], 0, 0, 0);
    __syncthreads();
  }

  int rb = m0 + wr + (lane >> 4) * 4;
  int cb = n0 + wc + lr;
#pragma unroll
  for (int mi = 0; mi < 4; ++mi) {
#pragma unroll
    for (int r = 0; r < 4; ++r) {
      int row = rb + mi * 16 + r;
#pragma unroll
      for (int ni = 0; ni < 4; ++ni) {
        int col = cb + ni * 16;
        float v = acc[mi][ni][r];
        size_t idx = (size_t)row * N + col;
        if (EPI == 0) {
          ((__bf16*)Cout)[idx] = (__bf16)v;
        } else if (EPI == 1) {
          ((float*)Cout)[idx] = resid[idx] + v + bias[col];
        } else if (EPI == 2) {
          v += bias[col];
          ((__bf16*)Cout)[idx] = (__bf16)fmaxf(v, 0.0f);
        } else if (EPI == 3) {
          ((float*)Cout)[idx] = resid[idx] + v + bias[col];
        } else {
          int b = row >> 11, t = row & 2047;
          int sel = col >> 10, cc = col & 1023, h = cc >> 6, d = cc & 63;
          int bh = b * 16 + h;
          __bf16 val = (__bf16)v;
          if (sel == 0)
            q_out[((size_t)bh * 64 + d) * 2048 + t] = val;   // Q transposed
          else if (sel == 1)
            k_out[((size_t)bh * 2048 + t) * 64 + d] = val;   // K row-major
          else
            vt_out[((size_t)bh * 64 + d) * 2048 + t] = val;  // V transposed
        }
      }
    }
  }
}

// ---------------- causal flash attention v3 (swapped QK^T, 32x32 MFMA) ------
// 4 waves/block, 32 q/wave (QBLK=128), KVBLK=64. Block handles q-tile pair
// (p, 15-p) sequentially -> uniform 34 kv-tiles/block.
// Qt: [BH][64][2048]  Kh: [BH][2048][64]  Vt: [BH][64][2048]  o: [B][T][1024]
__global__ __launch_bounds__(256) void attn_kernel3(const __bf16* __restrict__ Qt,
                                                    const __bf16* __restrict__ Kh,
                                                    const __bf16* __restrict__ Vt,
                                                    __bf16* __restrict__ o) {
  __shared__ __align__(16) char Klds[8192];  // 64 keys x 128B, XOR-swizzled
  __shared__ __align__(16) char Vlds[8192];  // 64 dims x 128B(64 keys), swizzled
  int tid = threadIdx.x;
  int l = tid & 63, w = tid >> 6;
  int lq = l & 31, hi = l >> 5;
  int p = blockIdx.x, bh = blockIdx.y;
  int b = bh >> 4, h = bh & 15;

  const char* Kbase = (const char*)(Kh + (size_t)bh * 2048 * 64);
  const char* Vbase = (const char*)(Vt + (size_t)bh * 64 * 2048);
  const __bf16* Qbase = Qt + (size_t)bh * 64 * 2048;
  __bf16* Obase = o + (size_t)b * 2048 * 1024 + h * 64;

  int srow = tid >> 3;
  int schunk = (tid & 7) * 16;
  int sw0 = (srow & 7) << 4;
  char* kd0 = Klds + tid * 16;
  char* kd1 = Klds + 4096 + tid * 16;
  char* vd0 = Vlds + tid * 16;
  char* vd1 = Vlds + 4096 + tid * 16;
  int swz = (lq & 7) << 4;

  for (int sweep = 0; sweep < 2; ++sweep) {
    int t = (sweep == 0) ? p : 15 - p;
    int qw = t * 128 + w * 32;
    int qglob = qw + lq;

    // Q B-fragments: qb[s][j] = Q[hs = s*16 + hi*8 + j][qw + lq]
    bf16x8 qb[4];
    const __bf16* qsrc = Qbase + (size_t)(hi * 8) * 2048 + qw + lq;
#pragma unroll
    for (int s = 0; s < 4; ++s)
#pragma unroll
      for (int j = 0; j < 8; ++j)
        qb[s][j] = qsrc[(size_t)(s * 16 + j) * 2048];

    f32x16 oacc0, oacc1;
#pragma unroll
    for (int i = 0; i < 16; ++i) { oacc0[i] = 0.0f; oacc1[i] = 0.0f; }
    float m_q = -3.0e38f, l_q = 0.0f;

    int nkb = 2 * t + 2;
    for (int kb = 0; kb < nkb; ++kb) {
      int s0 = kb * 64;
      __syncthreads();
      gload_lds16(Kbase + (size_t)(s0 + srow) * 128 + (schunk ^ sw0), kd0);
      gload_lds16(Kbase + (size_t)(s0 + srow + 32) * 128 + (schunk ^ sw0), kd1);
      gload_lds16(Vbase + (size_t)srow * 4096 + s0 * 2 + (schunk ^ sw0), vd0);
      gload_lds16(Vbase + (size_t)(srow + 32) * 4096 + s0 * 2 + (schunk ^ sw0), vd1);
      __syncthreads();

      // QK^T swapped: st[key][q], keys kg*32 + crow(r,hi)
      f32x16 st0, st1;
#pragma unroll
      for (int i = 0; i < 16; ++i) { st0[i] = 0.0f; st1[i] = 0.0f; }
#pragma unroll
      for (int s = 0; s < 4; ++s) {
        bf16x8 ka = *(const bf16x8*)(Klds + lq * 128 + ((s * 32 + hi * 16) ^ swz));
        st0 = __builtin_amdgcn_mfma_f32_32x32x16_bf16(ka, qb[s], st0, 0, 0, 0);
      }
#pragma unroll
      for (int s = 0; s < 4; ++s) {
        bf16x8 ka = *(const bf16x8*)(Klds + (32 + lq) * 128 + ((s * 32 + hi * 16) ^ swz));
        st1 = __builtin_amdgcn_mfma_f32_32x32x16_bf16(ka, qb[s], st1, 0, 0, 0);
      }
      // causal mask (raw scores; -1e38 -> exp2 underflows to 0)
#pragma unroll
      for (int r = 0; r < 16; ++r) {
        int key0 = s0 + (r & 3) + 8 * (r >> 2) + 4 * hi;
        if (key0 > qglob) st0[r] = -1.0e38f;
        if (key0 + 32 > qglob) st1[r] = -1.0e38f;
      }
      // in-lane max tree + cross-half permlane swap
      float mx8[8];
#pragma unroll
      for (int i = 0; i < 8; ++i)
        mx8[i] = fmaxf(fmaxf(st0[i], st0[i + 8]), fmaxf(st1[i], st1[i + 8]));
      float mx = fmaxf(fmaxf(fmaxf(mx8[0], mx8[1]), fmaxf(mx8[2], mx8[3])),
                       fmaxf(fmaxf(mx8[4], mx8[5]), fmaxf(mx8[6], mx8[7])));
      {
        float u = mx, v = mx;
        asm("v_permlane32_swap_b32 %0, %1" : "+v"(u), "+v"(v));
        mx = fmaxf(u, v);
      }
      float mt_s = mx * 0.03125f;
      // defer-max: rescale only when the running max grows past THR=8
      if (__any(mt_s > m_q + 8.0f)) {
        float mnew = fmaxf(m_q, mt_s);
        float scv = exp2f((m_q - mnew) * 1.44269504f);
        m_q = mnew;
        l_q *= scv;
#pragma unroll
        for (int r = 0; r < 16; ++r) {
          int qr = (r & 3) + 8 * (r >> 2) + 4 * hi;
          float scO = __shfl(scv, qr);
          oacc0[r] *= scO;
          oacc1[r] *= scO;
        }
      }
      float m2 = m_q * 1.44269504f;
#pragma unroll
      for (int r = 0; r < 16; ++r) {
        st0[r] = exp2f(fmaf(st0[r], 0.045084389f, -m2));
        st1[r] = exp2f(fmaf(st1[r], 0.045084389f, -m2));
      }
      // in-lane sum tree + permlane swap
      float s8[8];
#pragma unroll
      for (int i = 0; i < 8; ++i)
        s8[i] = (st0[i] + st0[i + 8]) + (st1[i] + st1[i + 8]);
      float ps = ((s8[0] + s8[1]) + (s8[2] + s8[3])) +
                 ((s8[4] + s8[5]) + (s8[6] + s8[7]));
      {
        float u = ps, v = ps;
        asm("v_permlane32_swap_b32 %0, %1" : "+v"(u), "+v"(v));
        ps = u + v;
      }
      l_q += ps;

      // pack P -> PV A-frags (cvt_pk + permlane32_swap), then PV MFMAs
      // kg = 0 (keys s0+0..31)
      {
        unsigned int w0 = cvt_pk(st0[0], st0[1]), w1 = cvt_pk(st0[2], st0[3]);
        unsigned int w2 = cvt_pk(st0[4], st0[5]), w3 = cvt_pk(st0[6], st0[7]);
        asm("v_permlane32_swap_b32 %0, %1" : "+v"(w0), "+v"(w2));
        asm("v_permlane32_swap_b32 %0, %1" : "+v"(w1), "+v"(w3));
        bf16x8 pa0 = pack_frag(w0, w1, w2, w3);
        unsigned int w4 = cvt_pk(st0[8], st0[9]), w5 = cvt_pk(st0[10], st0[11]);
        unsigned int w6 = cvt_pk(st0[12], st0[13]), w7 = cvt_pk(st0[14], st0[15]);
        asm("v_permlane32_swap_b32 %0, %1" : "+v"(w4), "+v"(w6));
        asm("v_permlane32_swap_b32 %0, %1" : "+v"(w5), "+v"(w7));
        bf16x8 pa1 = pack_frag(w4, w5, w6, w7);
        bf16x8 v00 = *(const bf16x8*)(Vlds + lq * 128 + ((hi * 16) ^ swz));
        bf16x8 v01 = *(const bf16x8*)(Vlds + (32 + lq) * 128 + ((hi * 16) ^ swz));
        bf16x8 v10 = *(const bf16x8*)(Vlds + lq * 128 + ((32 + hi * 16) ^ swz));
        bf16x8 v11 = *(const bf16x8*)(Vlds + (32 + lq) * 128 + ((32 + hi * 16) ^ swz));
        oacc0 = __builtin_amdgcn_mfma_f32_32x32x16_bf16(pa0, v00, oacc0, 0, 0, 0);
        oacc1 = __builtin_amdgcn_mfma_f32_32x32x16_bf16(pa0, v01, oacc1, 0, 0, 0);
        oacc0 = __builtin_amdgcn_mfma_f32_32x32x16_bf16(pa1, v10, oacc0, 0, 0, 0);
        oacc1 = __builtin_amdgcn_mfma_f32_32x32x16_bf16(pa1, v11, oacc1, 0, 0, 0);
      }
      // kg = 1 (keys s0+32..63)
      {
        unsigned int w0 = cvt_pk(st1[0], st1[1]), w1 = cvt_pk(st1[2], st1[3]);
        unsigned int w2 = cvt_pk(st1[4], st1[5]), w3 = cvt_pk(st1[6], st1[7]);
        asm("v_permlane32_swap_b32 %0, %1" : "+v"(w0), "+v"(w2));
        asm("v_permlane32_swap_b32 %0, %1" : "+v"(w1), "+v"(w3));
        bf16x8 pa0 = pack_frag(w0, w1, w2, w3);
        unsigned int w4 = cvt_pk(st1[8], st1[9]), w5 = cvt_pk(st1[10], st1[11]);
        unsigned int w6 = cvt_pk(st1[12], st1[13]), w7 = cvt_pk(st1[14], st1[15]);
        asm("v_permlane32_swap_b32 %0, %1" : "+v"(w4), "+v"(w6));
        asm("v_permlane32_swap_b32 %0, %1" : "+v"(w5), "+v"(w7));
        bf16x8 pa1 = pack_frag(w4, w5, w6, w7);
        bf16x8 v00 = *(const bf16x8*)(Vlds + lq * 128 + ((64 + hi * 16) ^ swz));
        bf16x8 v01 = *(const bf16x8*)(Vlds + (32 + lq) * 128 + ((64 + hi * 16) ^ swz));
        bf16x8 v10 = *(const bf16x8*)(Vlds + lq * 128 + ((96 + hi * 16) ^ swz));
        bf16x8 v11 = *(const bf16x8*)(Vlds + (32 + lq) * 128 + ((96 + hi * 16) ^ swz));
        oacc0 = __builtin_amdgcn_mfma_f32_32x32x16_bf16(pa0, v00, oacc0, 0, 0, 0);
        oacc1 = __builtin_amdgcn_mfma_f32_32x32x16_bf16(pa0, v01, oacc1, 0, 0, 0);
        oacc0 = __builtin_amdgcn_mfma_f32_32x32x16_bf16(pa1, v10, oacc0, 0, 0, 0);
        oacc1 = __builtin_amdgcn_mfma_f32_32x32x16_bf16(pa1, v11, oacc1, 0, 0, 0);
      }
    }
    // epilogue: normalize + write O
#pragma unroll
    for (int r = 0; r < 16; ++r) {
      int qr = (r & 3) + 8 * (r >> 2) + 4 * hi;
      float linv = 1.0f / __shfl(l_q, qr);
      size_t row = qw + qr;
      Obase[row * 1024 + lq] = (__bf16)(oacc0[r] * linv);
      Obase[row * 1024 + 32 + lq] = (__bf16)(oacc1[r] * linv);
    }
  }
}

// ---------------- launcher ----------------
extern "C" void kernel_launch(void* const* d_in, const int* in_sizes, int n_in,
                              void* d_out, int out_size, void* d_ws, size_t ws_size,
                              hipStream_t stream) {
  const float* x     = (const float*)d_in[0];
  const float* Wq    = (const float*)d_in[1];
  const float* Wk    = (const float*)d_in[2];
  const float* Wv    = (const float*)d_in[3];
  const float* Wproj = (const float*)d_in[4];
  const float* bproj = (const float*)d_in[5];
  const float* ln1_g = (const float*)d_in[6];
  const float* ln1_b = (const float*)d_in[7];
  const float* ln2_g = (const float*)d_in[8];
  const float* ln2_b = (const float*)d_in[9];
  const float* W1    = (const float*)d_in[10];
  const float* b1    = (const float*)d_in[11];
  const float* W2    = (const float*)d_in[12];
  const float* b2    = (const float*)d_in[13];
  float* out = (float*)d_out;

  char* ws = (char*)d_ws;
  __bf16* actA   = (__bf16*)(ws + 0);          // 16 MB
  __bf16* WqkvT  = (__bf16*)(ws + 16777216);   // 6 MB
  __bf16* WprojT = (__bf16*)(ws + 23068672);   // 2 MB
  __bf16* W1T    = (__bf16*)(ws + 25165824);   // 8 MB
  __bf16* W2T    = (__bf16*)(ws + 33554432);   // 8 MB
  __bf16* Qt     = (__bf16*)(ws + 41943040);   // 16 MB
  __bf16* Kh     = (__bf16*)(ws + 58720256);   // 16 MB
  __bf16* Vt     = (__bf16*)(ws + 75497472);   // 16 MB
  __bf16* obuf   = (__bf16*)(ws + 92274688);   // 16 MB
  __bf16* ff1    = Qt;                         // 64 MB, reuses Qt..obuf (dead by then)

  dim3 t32x8(32, 8);
  qkv_repack<<<dim3(2, 32, 48), t32x8, 0, stream>>>(Wq, Wk, Wv, WqkvT);
  transpose_cvt<<<dim3(32, 32), t32x8, 0, stream>>>(Wproj, WprojT, 1024, 1024);
  transpose_cvt<<<dim3(128, 32), t32x8, 0, stream>>>(W1, W1T, 1024, 4096);
  transpose_cvt<<<dim3(32, 128), t32x8, 0, stream>>>(W2, W2T, 4096, 1024);

  ln_kernel<<<8192, 256, 0, stream>>>(x, ln1_g, ln1_b, actA);
  gemm_bt<4><<<dim3(24, 64), 256, 0, stream>>>(actA, WqkvT, nullptr, nullptr, nullptr,
                                               Qt, Kh, Vt, 8192, 3072, 1024);
  attn_kernel3<<<dim3(8, 64), 256, 0, stream>>>(Qt, Kh, Vt, obuf);
  gemm_bt<1><<<dim3(8, 64), 256, 0, stream>>>(obuf, WprojT, out, bproj, x,
                                              nullptr, nullptr, nullptr, 8192, 1024, 1024);
  ln_kernel<<<8192, 256, 0, stream>>>(out, ln2_g, ln2_b, actA);
  gemm_bt<2><<<dim3(32, 64), 256, 0, stream>>>(actA, W1T, ff1, b1, nullptr,
                                               nullptr, nullptr, nullptr, 8192, 4096, 1024);
  gemm_bt<3><<<dim3(8, 64), 256, 0, stream>>>(ff1, W2T, out, b2, out,
                                              nullptr, nullptr, nullptr, 8192, 1024, 4096);
}